// Round 1
// baseline (99.138 us; speedup 1.0000x reference)
//
#include <hip/hip_runtime.h>

#define BATCH 32
#define SEQ   2048
#define KD    512
#define QD    1024
#define HD    128

#define BM 128
#define BK 64

typedef float  f32x4  __attribute__((ext_vector_type(4)));
typedef short  bf16x8 __attribute__((ext_vector_type(8)));

typedef unsigned int   u32;
typedef unsigned short u16;

__device__ __forceinline__ u16 f2bf(float x) {
    u32 u = __float_as_uint(x);
    u32 r = (u + 0x7fffu + ((u >> 16) & 1u)) >> 16;  // RNE to bf16
    return (u16)r;
}
__device__ __forceinline__ float bf2f(u16 h) {
    return __uint_as_float(((u32)h) << 16);
}

// ---------------------------------------------------------------- q_proj
// q_proj[b,h] = sum_k query[b,k] * W1[h,k].  grid = B*H blocks of 64.
__global__ __launch_bounds__(64) void qproj_kernel(
        const float* __restrict__ query, const float* __restrict__ W1,
        float* __restrict__ qp) {
    int b = blockIdx.x >> 7;
    int h = blockIdx.x & 127;
    const float* q = query + (size_t)b * QD;
    const float* w = W1 + (size_t)h * QD;
    int lane = threadIdx.x;
    float acc = 0.f;
    #pragma unroll
    for (int k = 0; k < QD; k += 256) {
        float4 qv = *(const float4*)(q + k + lane * 4);
        float4 wv = *(const float4*)(w + k + lane * 4);
        acc += qv.x * wv.x + qv.y * wv.y + qv.z * wv.z + qv.w * wv.w;
    }
    #pragma unroll
    for (int off = 32; off >= 1; off >>= 1) acc += __shfl_xor(acc, off);
    if (lane == 0) qp[b * HD + h] = acc;
}

// ---------------------------------------------------------------- score
// score[m] = sum_h tanh(qp[b,h] + sum_k keys[m,k]*W2[h,k]) * V[h]
// Split-bf16 MFMA GEMM: acc += ah*bh + ah*bl + al*bh  (al*bl dropped).
__global__ __launch_bounds__(256, 2) void score_kernel(
        const float* __restrict__ keys, const float* __restrict__ W2,
        const float* __restrict__ qp, const float* __restrict__ V,
        float* __restrict__ score) {
    __shared__ char lds[4 * BM * BK * 2];  // 64 KiB
    char* Ah = lds;
    char* Al = lds + 16384;
    char* Bh = lds + 32768;
    char* Bl = lds + 49152;

    const int m0   = blockIdx.x * BM;
    const int b    = m0 / SEQ;
    const int tid  = threadIdx.x;
    const int wave = tid >> 6;
    const int lane = tid & 63;
    const int l15  = lane & 15;
    const int l4   = lane >> 4;

    f32x4 acc[2][8];
    #pragma unroll
    for (int mi = 0; mi < 2; ++mi)
        #pragma unroll
        for (int hj = 0; hj < 8; ++hj)
            acc[mi][hj] = (f32x4)0.f;

    for (int kc = 0; kc < KD; kc += BK) {
        __syncthreads();  // previous compute done reading LDS
        // stage: first 1024 slots -> keys tile (A), next 1024 -> W2 tile (B)
        #pragma unroll
        for (int it = 0; it < 8; ++it) {
            int idx  = it * 256 + tid;       // 0..2047
            int half = idx >> 10;            // 0=A 1=B
            int sub  = idx & 1023;
            int row  = sub >> 3;             // 0..127
            int kq   = (sub & 7) * 8;        // 0,8,..,56
            const float* src = (half == 0)
                ? keys + (size_t)(m0 + row) * KD + kc + kq
                : W2   + (size_t)row * KD + kc + kq;
            float4 v0 = *(const float4*)(src);
            float4 v1 = *(const float4*)(src + 4);
            float xs[8] = {v0.x, v0.y, v0.z, v0.w, v1.x, v1.y, v1.z, v1.w};
            u32 hu[4], lu[4];
            #pragma unroll
            for (int p = 0; p < 4; ++p) {
                u16 h0 = f2bf(xs[2 * p]);
                u16 h1 = f2bf(xs[2 * p + 1]);
                float r0 = xs[2 * p]     - bf2f(h0);
                float r1 = xs[2 * p + 1] - bf2f(h1);
                u16 l0 = f2bf(r0);
                u16 l1 = f2bf(r1);
                hu[p] = (u32)h0 | ((u32)h1 << 16);
                lu[p] = (u32)l0 | ((u32)l1 << 16);
            }
            int off = ((row * BK + kq) * 2) ^ ((row & 7) << 4);
            char* dh = (half ? Bh : Ah) + off;
            char* dl = (half ? Bl : Al) + off;
            *(uint4*)dh = make_uint4(hu[0], hu[1], hu[2], hu[3]);
            *(uint4*)dl = make_uint4(lu[0], lu[1], lu[2], lu[3]);
        }
        __syncthreads();

        #pragma unroll
        for (int ks = 0; ks < 2; ++ks) {
            int kb = ks * 32 + l4 * 8;  // k element within BK
            bf16x8 ah[2], al[2];
            #pragma unroll
            for (int mi = 0; mi < 2; ++mi) {
                int row = wave * 32 + mi * 16 + l15;
                int off = ((row * BK + kb) * 2) ^ ((row & 7) << 4);
                ah[mi] = *(const bf16x8*)(Ah + off);
                al[mi] = *(const bf16x8*)(Al + off);
            }
            #pragma unroll
            for (int hj = 0; hj < 8; ++hj) {
                int hrow = hj * 16 + l15;
                int off  = ((hrow * BK + kb) * 2) ^ ((hrow & 7) << 4);
                bf16x8 bh = *(const bf16x8*)(Bh + off);
                bf16x8 bl = *(const bf16x8*)(Bl + off);
                #pragma unroll
                for (int mi = 0; mi < 2; ++mi) {
                    acc[mi][hj] = __builtin_amdgcn_mfma_f32_16x16x32_bf16(
                        ah[mi], bh, acc[mi][hj], 0, 0, 0);
                    acc[mi][hj] = __builtin_amdgcn_mfma_f32_16x16x32_bf16(
                        ah[mi], bl, acc[mi][hj], 0, 0, 0);
                    acc[mi][hj] = __builtin_amdgcn_mfma_f32_16x16x32_bf16(
                        al[mi], bh, acc[mi][hj], 0, 0, 0);
                }
            }
        }
    }

    // epilogue: C/D layout is col = lane&15, row = (lane>>4)*4 + reg
    float qv[8], vv[8];
    #pragma unroll
    for (int hj = 0; hj < 8; ++hj) {
        int h = hj * 16 + l15;
        qv[hj] = qp[b * HD + h];
        vv[hj] = V[h];
    }
    #pragma unroll
    for (int mi = 0; mi < 2; ++mi) {
        #pragma unroll
        for (int j = 0; j < 4; ++j) {
            float p = 0.f;
            #pragma unroll
            for (int hj = 0; hj < 8; ++hj)
                p += tanhf(qv[hj] + acc[mi][hj][j]) * vv[hj];
            #pragma unroll
            for (int off = 1; off < 16; off <<= 1) p += __shfl_xor(p, off);
            if (l15 == 0) {
                int m = m0 + wave * 32 + mi * 16 + l4 * 4 + j;
                score[m] = p;
            }
        }
    }
}

// ---------------------------------------------------------------- softmax
// in-place over each row of 2048
__global__ __launch_bounds__(256) void softmax_kernel(float* __restrict__ w) {
    float* row = w + (size_t)blockIdx.x * SEQ;
    int tid  = threadIdx.x;
    int wave = tid >> 6, lane = tid & 63;
    float v[8];
    float mx = -1e30f;
    #pragma unroll
    for (int i = 0; i < 8; ++i) {
        v[i] = row[tid + 256 * i];
        mx = fmaxf(mx, v[i]);
    }
    #pragma unroll
    for (int off = 32; off >= 1; off >>= 1) mx = fmaxf(mx, __shfl_xor(mx, off));
    __shared__ float redm[4], reds[4];
    if (lane == 0) redm[wave] = mx;
    __syncthreads();
    mx = fmaxf(fmaxf(redm[0], redm[1]), fmaxf(redm[2], redm[3]));
    float s = 0.f;
    #pragma unroll
    for (int i = 0; i < 8; ++i) {
        v[i] = __expf(v[i] - mx);
        s += v[i];
    }
    #pragma unroll
    for (int off = 32; off >= 1; off >>= 1) s += __shfl_xor(s, off);
    if (lane == 0) reds[wave] = s;
    __syncthreads();
    s = reds[0] + reds[1] + reds[2] + reds[3];
    float inv = 1.f / s;
    #pragma unroll
    for (int i = 0; i < 8; ++i) row[tid + 256 * i] = v[i] * inv;
}

// ---------------------------------------------------------------- context
// partial[b,c,k] = sum_{s in chunk c} w[b,s]*keys[b,s,k]
__global__ __launch_bounds__(128) void ctx_partial_kernel(
        const float* __restrict__ keys, const float* __restrict__ w,
        float* __restrict__ part, int nchunk) {
    int blk = blockIdx.x;
    int b = blk / nchunk;
    int c = blk % nchunk;
    int rows = SEQ / nchunk;
    int kq = threadIdx.x * 4;
    f32x4 acc = (f32x4)0.f;
    int s0 = c * rows;
    const float* kb = keys + (size_t)b * SEQ * KD;
    for (int s = s0; s < s0 + rows; ++s) {
        float ws = w[b * SEQ + s];
        f32x4 kv = *(const f32x4*)(kb + (size_t)s * KD + kq);
        acc += ws * kv;
    }
    *(f32x4*)(part + (size_t)blk * KD + kq) = acc;
}

__global__ __launch_bounds__(128) void ctx_reduce_kernel(
        const float* __restrict__ part, float* __restrict__ ctx, int nchunk) {
    int b = blockIdx.x;
    int kq = threadIdx.x * 4;
    f32x4 acc = (f32x4)0.f;
    for (int c = 0; c < nchunk; ++c)
        acc += *(const f32x4*)(part + (size_t)(b * nchunk + c) * KD + kq);
    *(f32x4*)(ctx + (size_t)b * KD + kq) = acc;
}

// ---------------------------------------------------------------- launch
extern "C" void kernel_launch(void* const* d_in, const int* in_sizes, int n_in,
                              void* d_out, int out_size, void* d_ws, size_t ws_size,
                              hipStream_t stream) {
    const float* query = (const float*)d_in[0];
    const float* keys  = (const float*)d_in[1];
    const float* W1    = (const float*)d_in[2];
    const float* W2    = (const float*)d_in[3];
    const float* V     = (const float*)d_in[4];

    float* ctx = (float*)d_out;                   // [32*512]
    float* wts = (float*)d_out + BATCH * KD;      // [32*2048] (scores -> weights)

    float* qp   = (float*)d_ws;                   // 32*128 floats
    float* part = (float*)d_ws + BATCH * HD;

    int nchunk = 64;
    size_t need = (size_t)BATCH * HD * 4 + (size_t)BATCH * 64 * KD * 4;
    if (ws_size < need) nchunk = 8;

    qproj_kernel<<<BATCH * HD, 64, 0, stream>>>(query, W1, qp);
    score_kernel<<<(BATCH * SEQ) / BM, 256, 0, stream>>>(keys, W2, qp, V, wts);
    softmax_kernel<<<BATCH, 256, 0, stream>>>(wts);
    ctx_partial_kernel<<<BATCH * nchunk, 128, 0, stream>>>(keys, wts, part, nchunk);
    ctx_reduce_kernel<<<BATCH, 128, 0, stream>>>(part, ctx, nchunk);
}

// Round 2
// 82.072 us; speedup vs baseline: 1.2079x; 1.2079x over previous
//
#include <hip/hip_runtime.h>

#define BATCH 32
#define SEQ   2048
#define KD    512
#define QD    1024
#define HD    128

#define BM 128
#define BK 32
#define NT (KD / BK)   // 16 K-steps

typedef float  f32x4  __attribute__((ext_vector_type(4)));
typedef short  bf16x8 __attribute__((ext_vector_type(8)));
typedef unsigned int u32;

// truncation split: hi = top 16 bits of fp32, lo = bf16_trunc(x - hi)
// pack two floats' bf16 into one u32 with a single v_perm_b32
__device__ __forceinline__ void splitpair(float x0, float x1, u32& ho, u32& lo) {
    u32 u0 = __float_as_uint(x0), u1 = __float_as_uint(x1);
    float h0 = __uint_as_float(u0 & 0xFFFF0000u);
    float h1 = __uint_as_float(u1 & 0xFFFF0000u);
    ho = __builtin_amdgcn_perm(u1, u0, 0x07060302);   // bf16(x0) | bf16(x1)<<16
    float r0 = x0 - h0, r1 = x1 - h1;
    lo = __builtin_amdgcn_perm(__float_as_uint(r1), __float_as_uint(r0), 0x07060302);
}

__device__ __forceinline__ void split16(const f32x4 a[4], uint4& h0, uint4& h1,
                                        uint4& l0, uint4& l1) {
    u32 h[8], l[8];
    #pragma unroll
    for (int i = 0; i < 4; ++i) {
        splitpair(a[i][0], a[i][1], h[2 * i], l[2 * i]);
        splitpair(a[i][2], a[i][3], h[2 * i + 1], l[2 * i + 1]);
    }
    h0 = make_uint4(h[0], h[1], h[2], h[3]);
    h1 = make_uint4(h[4], h[5], h[6], h[7]);
    l0 = make_uint4(l[0], l[1], l[2], l[3]);
    l1 = make_uint4(l[4], l[5], l[6], l[7]);
}

__device__ __forceinline__ void gload_lds16(const void* g, void* l) {
    __builtin_amdgcn_global_load_lds(
        (const __attribute__((address_space(1))) unsigned int*)g,
        (__attribute__((address_space(3))) unsigned int*)l, 16, 0, 0);
}

// ---------------------------------------------------------------- q_proj
__global__ __launch_bounds__(64) void qproj_kernel(
        const float* __restrict__ query, const float* __restrict__ W1,
        float* __restrict__ qp) {
    int b = blockIdx.x >> 7;
    int h = blockIdx.x & 127;
    const float* q = query + (size_t)b * QD;
    const float* w = W1 + (size_t)h * QD;
    int lane = threadIdx.x;
    float acc = 0.f;
    #pragma unroll
    for (int k = 0; k < QD; k += 256) {
        float4 qv = *(const float4*)(q + k + lane * 4);
        float4 wv = *(const float4*)(w + k + lane * 4);
        acc += qv.x * wv.x + qv.y * wv.y + qv.z * wv.z + qv.w * wv.w;
    }
    #pragma unroll
    for (int off = 32; off >= 1; off >>= 1) acc += __shfl_xor(acc, off);
    if (lane == 0) qp[b * HD + h] = acc;
}

// ---------------------------------------------------------------- W2 prep
// convert W2 -> swizzled bf16 hi/lo tile images, one 8192-B tile per K-step,
// laid out so a LINEAR global_load_lds copy lands in XOR-swizzled LDS form.
__global__ __launch_bounds__(256) void prep_w2(const float* __restrict__ W2,
        char* __restrict__ swh, char* __restrict__ swl) {
    int c = blockIdx.x;             // K chunk 0..NT-1
    int tid = threadIdx.x;
    int row = tid >> 1;             // h row 0..127
    int scol = (tid & 1) * 16;      // element col within BK
    const float* src = W2 + (size_t)row * KD + c * BK + scol;
    f32x4 a[4];
    #pragma unroll
    for (int i = 0; i < 4; ++i) a[i] = *(const f32x4*)(src + i * 4);
    uint4 h0, h1, l0, l1;
    split16(a, h0, h1, l0, l1);
    int sw = (row & 7) << 4;
    int b0 = c * 8192 + ((row * 64 + scol * 2) ^ sw);
    int b1 = c * 8192 + ((row * 64 + scol * 2 + 16) ^ sw);
    *(uint4*)(swh + b0) = h0; *(uint4*)(swh + b1) = h1;
    *(uint4*)(swl + b0) = l0; *(uint4*)(swl + b1) = l1;
}

// ---------------------------------------------------------------- score
__global__ __launch_bounds__(256, 2) void score_kernel(
        const float* __restrict__ keys, const char* __restrict__ w2swh,
        const char* __restrict__ w2swl, const float* __restrict__ qp,
        const float* __restrict__ V, float* __restrict__ score) {
    // [buf][Ah,Al,Bh,Bl][128*32*2 bytes]  = 64 KiB
    __shared__ char lds[2][4][BM * BK * 2];

    const int m0   = blockIdx.x * BM;
    const int b    = m0 / SEQ;
    const int tid  = threadIdx.x;
    const int wave = tid >> 6;
    const int lane = tid & 63;
    const int l15  = lane & 15;
    const int l4   = lane >> 4;

    // staging coords (A tile): thread -> (row, 16-elem half)
    const int srow = tid >> 1;
    const int scol = (tid & 1) * 16;
    const int ssw  = (srow & 7) << 4;
    const int sb0  = (srow * 64 + scol * 2) ^ ssw;
    const int sb1  = (srow * 64 + scol * 2 + 16) ^ ssw;
    const float* asrc = keys + (size_t)(m0 + srow) * KD + scol;

    // epilogue operands (hide latency: load now)
    float qv[8], vv[8];
    #pragma unroll
    for (int hj = 0; hj < 8; ++hj) {
        qv[hj] = qp[b * HD + hj * 16 + l15];
        vv[hj] = V[hj * 16 + l15];
    }

    // fragment byte offsets within an 8192-B tile
    const int boff0 = (l15 * 64 + l4 * 16) ^ ((l15 & 7) << 4);
    const int aoff0 = boff0 + wave * 2048;     // mi=0 row block
    const int aoff1 = aoff0 + 1024;            // mi=1

    f32x4 acc[2][8];
    #pragma unroll
    for (int mi = 0; mi < 2; ++mi)
        #pragma unroll
        for (int hj = 0; hj < 8; ++hj)
            acc[mi][hj] = (f32x4)0.f;

    // ---- prologue: stage tile 0 into buf 0
    {
        const char* gH = w2swh + wave * 2048 + lane * 16;
        const char* gL = w2swl + wave * 2048 + lane * 16;
        gload_lds16(gH,        &lds[0][2][wave * 2048]);
        gload_lds16(gH + 1024, &lds[0][2][wave * 2048 + 1024]);
        gload_lds16(gL,        &lds[0][3][wave * 2048]);
        gload_lds16(gL + 1024, &lds[0][3][wave * 2048 + 1024]);
        f32x4 a[4];
        #pragma unroll
        for (int i = 0; i < 4; ++i) a[i] = *(const f32x4*)(asrc + i * 4);
        uint4 h0, h1, l0, l1;
        split16(a, h0, h1, l0, l1);
        *(uint4*)&lds[0][0][sb0] = h0;
        *(uint4*)&lds[0][0][sb1] = h1;
        *(uint4*)&lds[0][1][sb0] = l0;
        *(uint4*)&lds[0][1][sb1] = l1;
    }
    __syncthreads();

    // ---- main loop: prefetch t+1 while computing t
    for (int t = 0; t < NT; ++t) {
        const int cb = t & 1, nb = cb ^ 1;
        f32x4 a[4];
        if (t + 1 < NT) {
            const char* gH = w2swh + (t + 1) * 8192 + wave * 2048 + lane * 16;
            const char* gL = w2swl + (t + 1) * 8192 + wave * 2048 + lane * 16;
            gload_lds16(gH,        &lds[nb][2][wave * 2048]);
            gload_lds16(gH + 1024, &lds[nb][2][wave * 2048 + 1024]);
            gload_lds16(gL,        &lds[nb][3][wave * 2048]);
            gload_lds16(gL + 1024, &lds[nb][3][wave * 2048 + 1024]);
            const float* s = asrc + (t + 1) * BK;
            #pragma unroll
            for (int i = 0; i < 4; ++i) a[i] = *(const f32x4*)(s + i * 4);
        }

        bf16x8 ah0 = *(const bf16x8*)&lds[cb][0][aoff0];
        bf16x8 ah1 = *(const bf16x8*)&lds[cb][0][aoff1];
        bf16x8 al0 = *(const bf16x8*)&lds[cb][1][aoff0];
        bf16x8 al1 = *(const bf16x8*)&lds[cb][1][aoff1];
        #pragma unroll
        for (int hj = 0; hj < 8; ++hj) {
            bf16x8 bh = *(const bf16x8*)&lds[cb][2][boff0 + hj * 1024];
            bf16x8 bl = *(const bf16x8*)&lds[cb][3][boff0 + hj * 1024];
            acc[0][hj] = __builtin_amdgcn_mfma_f32_16x16x32_bf16(ah0, bh, acc[0][hj], 0, 0, 0);
            acc[0][hj] = __builtin_amdgcn_mfma_f32_16x16x32_bf16(ah0, bl, acc[0][hj], 0, 0, 0);
            acc[0][hj] = __builtin_amdgcn_mfma_f32_16x16x32_bf16(al0, bh, acc[0][hj], 0, 0, 0);
            acc[1][hj] = __builtin_amdgcn_mfma_f32_16x16x32_bf16(ah1, bh, acc[1][hj], 0, 0, 0);
            acc[1][hj] = __builtin_amdgcn_mfma_f32_16x16x32_bf16(ah1, bl, acc[1][hj], 0, 0, 0);
            acc[1][hj] = __builtin_amdgcn_mfma_f32_16x16x32_bf16(al1, bh, acc[1][hj], 0, 0, 0);
        }

        if (t + 1 < NT) {
            uint4 h0, h1, l0, l1;
            split16(a, h0, h1, l0, l1);
            *(uint4*)&lds[nb][0][sb0] = h0;
            *(uint4*)&lds[nb][0][sb1] = h1;
            *(uint4*)&lds[nb][1][sb0] = l0;
            *(uint4*)&lds[nb][1][sb1] = l1;
        }
        __syncthreads();
    }

    // ---- epilogue: tanh + V-dot + 16-lane reduce; C/D: col=l15, row=l4*4+j
    #pragma unroll
    for (int mi = 0; mi < 2; ++mi) {
        #pragma unroll
        for (int j = 0; j < 4; ++j) {
            float p = 0.f;
            #pragma unroll
            for (int hj = 0; hj < 8; ++hj) {
                float x = qv[hj] + acc[mi][hj][j];
                float e = __expf(2.f * x);
                float th = 1.f - 2.f * __builtin_amdgcn_rcpf(1.f + e);
                p += th * vv[hj];
            }
            #pragma unroll
            for (int off = 1; off < 16; off <<= 1) p += __shfl_xor(p, off);
            if (l15 == 0) score[m0 + wave * 32 + mi * 16 + l4 * 4 + j] = p;
        }
    }
}

// ---------------------------------------------------------------- softmax
__global__ __launch_bounds__(256) void softmax_kernel(float* __restrict__ w) {
    float* row = w + (size_t)blockIdx.x * SEQ;
    int tid = threadIdx.x;
    int wave = tid >> 6, lane = tid & 63;
    float v[8];
    float mx = -1e30f;
    #pragma unroll
    for (int i = 0; i < 8; ++i) {
        v[i] = row[tid + 256 * i];
        mx = fmaxf(mx, v[i]);
    }
    #pragma unroll
    for (int off = 32; off >= 1; off >>= 1) mx = fmaxf(mx, __shfl_xor(mx, off));
    __shared__ float redm[4], reds[4];
    if (lane == 0) redm[wave] = mx;
    __syncthreads();
    mx = fmaxf(fmaxf(redm[0], redm[1]), fmaxf(redm[2], redm[3]));
    float s = 0.f;
    #pragma unroll
    for (int i = 0; i < 8; ++i) {
        v[i] = __expf(v[i] - mx);
        s += v[i];
    }
    #pragma unroll
    for (int off = 32; off >= 1; off >>= 1) s += __shfl_xor(s, off);
    if (lane == 0) reds[wave] = s;
    __syncthreads();
    s = reds[0] + reds[1] + reds[2] + reds[3];
    float inv = 1.f / s;
    #pragma unroll
    for (int i = 0; i < 8; ++i) row[tid + 256 * i] = v[i] * inv;
}

// ---------------------------------------------------------------- context
__global__ __launch_bounds__(128) void ctx_partial_kernel(
        const float* __restrict__ keys, const float* __restrict__ w,
        float* __restrict__ part, int nchunk) {
    int blk = blockIdx.x;
    int b = blk / nchunk;
    int c = blk % nchunk;
    int rows = SEQ / nchunk;
    int kq = threadIdx.x * 4;
    f32x4 acc = (f32x4)0.f;
    int s0 = c * rows;
    const float* kb = keys + (size_t)b * SEQ * KD;
    for (int s = s0; s < s0 + rows; ++s) {
        float ws = w[b * SEQ + s];
        f32x4 kv = *(const f32x4*)(kb + (size_t)s * KD + kq);
        acc += ws * kv;
    }
    *(f32x4*)(part + (size_t)blk * KD + kq) = acc;
}

__global__ __launch_bounds__(128) void ctx_reduce_kernel(
        const float* __restrict__ part, float* __restrict__ ctx, int nchunk) {
    int b = blockIdx.x;
    int kq = threadIdx.x * 4;
    f32x4 acc = (f32x4)0.f;
    for (int c = 0; c < nchunk; ++c)
        acc += *(const f32x4*)(part + (size_t)(b * nchunk + c) * KD + kq);
    *(f32x4*)(ctx + (size_t)b * KD + kq) = acc;
}

// ---------------------------------------------------------------- launch
extern "C" void kernel_launch(void* const* d_in, const int* in_sizes, int n_in,
                              void* d_out, int out_size, void* d_ws, size_t ws_size,
                              hipStream_t stream) {
    const float* query = (const float*)d_in[0];
    const float* keys  = (const float*)d_in[1];
    const float* W1    = (const float*)d_in[2];
    const float* W2    = (const float*)d_in[3];
    const float* V     = (const float*)d_in[4];

    float* ctx = (float*)d_out;
    float* wts = (float*)d_out + BATCH * KD;

    char* wsb  = (char*)d_ws;
    float* qp  = (float*)wsb;                          // 16 KB
    char* w2h  = wsb + 16 * 1024;                      // 128 KB
    char* w2l  = wsb + 16 * 1024 + 128 * 1024;         // 128 KB
    size_t pbase = 16 * 1024 + 256 * 1024;
    float* part = (float*)(wsb + pbase);

    int nchunk = 64;
    if (ws_size < pbase + (size_t)BATCH * 64 * KD * 4) nchunk = 8;
    if (ws_size < pbase + (size_t)BATCH * 8 * KD * 4) nchunk = 1;

    qproj_kernel<<<BATCH * HD, 64, 0, stream>>>(query, W1, qp);
    prep_w2<<<NT, 256, 0, stream>>>(W2, w2h, w2l);
    score_kernel<<<(BATCH * SEQ) / BM, 256, 0, stream>>>(keys, w2h, w2l, qp, V, wts);
    softmax_kernel<<<BATCH, 256, 0, stream>>>(wts);
    ctx_partial_kernel<<<BATCH * nchunk, 128, 0, stream>>>(keys, wts, part, nchunk);
    ctx_reduce_kernel<<<BATCH, 128, 0, stream>>>(part, ctx, nchunk);
}

// Round 3
// 52.012 us; speedup vs baseline: 1.9061x; 1.5780x over previous
//
#include <hip/hip_runtime.h>

#define BATCH 32
#define SEQ   2048
#define KD    512
#define QD    1024
#define HD    128

#define BM 128
#define BK 32
#define NT (KD / BK)   // 16 K-steps

typedef float    f32x4 __attribute__((ext_vector_type(4)));
typedef _Float16 f16x8 __attribute__((ext_vector_type(8)));
typedef unsigned int u32;

__device__ __forceinline__ u32 pack2h(float a, float b) {
    _Float16 ha = (_Float16)a, hb = (_Float16)b;   // v_cvt_f16_f32 (RNE)
    unsigned short ua = __builtin_bit_cast(unsigned short, ha);
    unsigned short ub = __builtin_bit_cast(unsigned short, hb);
    return (u32)ua | ((u32)ub << 16);
}

// 16 fp32 -> 16 f16 packed in two uint4 (bytes [0,16) and [16,32))
__device__ __forceinline__ void cvt16(const f32x4 a[4], uint4& h0, uint4& h1) {
    h0 = make_uint4(pack2h(a[0][0], a[0][1]), pack2h(a[0][2], a[0][3]),
                    pack2h(a[1][0], a[1][1]), pack2h(a[1][2], a[1][3]));
    h1 = make_uint4(pack2h(a[2][0], a[2][1]), pack2h(a[2][2], a[2][3]),
                    pack2h(a[3][0], a[3][1]), pack2h(a[3][2], a[3][3]));
}

__device__ __forceinline__ void gload_lds16(const void* g, void* l) {
    __builtin_amdgcn_global_load_lds(
        (const __attribute__((address_space(1))) unsigned int*)g,
        (__attribute__((address_space(3))) unsigned int*)l, 16, 0, 0);
}

// ---------------------------------------------------------------- prep
// blocks [0,512): q_proj  (block = (b, group of 8 h), 4 waves x 2 h each)
// blocks [512,528): W2 -> f16 swizzled tile images (8 KB per K-step)
__global__ __launch_bounds__(256) void prep_kernel(
        const float* __restrict__ query, const float* __restrict__ W1,
        const float* __restrict__ W2, float* __restrict__ qp,
        char* __restrict__ w2img) {
    int blk = blockIdx.x;
    int tid = threadIdx.x;
    if (blk < 512) {
        int b = blk >> 4, hg = blk & 15;
        int wave = tid >> 6, lane = tid & 63;
        int h = hg * 8 + wave * 2 + (lane >> 5);
        int l32 = lane & 31;
        const float* q = query + (size_t)b * QD;
        const float* w = W1 + (size_t)h * QD;
        float acc = 0.f;
        #pragma unroll
        for (int i = 0; i < 8; ++i) {
            float4 qv = *(const float4*)(q + i * 128 + l32 * 4);
            float4 wv = *(const float4*)(w + i * 128 + l32 * 4);
            acc += qv.x * wv.x + qv.y * wv.y + qv.z * wv.z + qv.w * wv.w;
        }
        #pragma unroll
        for (int off = 16; off >= 1; off >>= 1) acc += __shfl_xor(acc, off);
        if (l32 == 0) qp[b * HD + h] = acc;
    } else {
        int c = blk - 512;              // K chunk
        int row = tid >> 1;             // h row 0..127
        int scol = (tid & 1) * 16;
        const float* src = W2 + (size_t)row * KD + c * BK + scol;
        f32x4 a[4];
        #pragma unroll
        for (int i = 0; i < 4; ++i) a[i] = *(const f32x4*)(src + i * 4);
        uint4 h0, h1;
        cvt16(a, h0, h1);
        int sw = (row & 7) << 4;
        int b0 = c * 8192 + ((row * 64 + scol * 2) ^ sw);
        int b1 = c * 8192 + ((row * 64 + scol * 2 + 16) ^ sw);
        *(uint4*)(w2img + b0) = h0;
        *(uint4*)(w2img + b1) = h1;
    }
}

// ---------------------------------------------------------------- score + ctx partial
__global__ __launch_bounds__(256, 2) void score_ctx_kernel(
        const float* __restrict__ keys, const char* __restrict__ w2img,
        const float* __restrict__ qp, const float* __restrict__ V,
        float* __restrict__ score_out, float* __restrict__ part_m,
        float* __restrict__ part_l, float* __restrict__ part_c) {
    __shared__ __align__(16) char lds[34048];
    char* A = lds;             // [2][8192] f16 swizzled
    char* B = lds + 16384;     // [2][8192]
    float* sc  = (float*)(lds + 32768);        // 128 raw scores
    float* pb  = (float*)(lds + 32768 + 512);  // 128 exp weights
    float* red = (float*)(lds + 32768 + 1024); // 8

    const int blk = blockIdx.x;
    const int m0  = blk * BM;
    const int b   = blk >> 4;          // 16 blocks per batch
    const int tid = threadIdx.x;
    const int wave = tid >> 6;
    const int lane = tid & 63;
    const int l15  = lane & 15;
    const int l4   = lane >> 4;

    // staging coords
    const int srow = tid >> 1;
    const int scol = (tid & 1) * 16;
    const int ssw  = (srow & 7) << 4;
    const int sb0  = (srow * 64 + scol * 2) ^ ssw;
    const int sb1  = (srow * 64 + scol * 2 + 16) ^ ssw;
    const float* asrc = keys + (size_t)(m0 + srow) * KD + scol;

    // epilogue operands
    float qv[8], vv[8];
    #pragma unroll
    for (int hj = 0; hj < 8; ++hj) {
        qv[hj] = qp[b * HD + hj * 16 + l15];
        vv[hj] = V[hj * 16 + l15];
    }

    const int boff0 = (l15 * 64 + l4 * 16) ^ ((l15 & 7) << 4);
    const int aoff0 = boff0 + wave * 2048;
    const int aoff1 = aoff0 + 1024;

    f32x4 acc[2][8];
    #pragma unroll
    for (int mi = 0; mi < 2; ++mi)
        #pragma unroll
        for (int hj = 0; hj < 8; ++hj)
            acc[mi][hj] = (f32x4)0.f;

    // prologue: stage tile 0 into buf 0
    {
        const char* g = w2img + wave * 2048 + lane * 16;
        gload_lds16(g,        B + wave * 2048);
        gload_lds16(g + 1024, B + wave * 2048 + 1024);
        f32x4 a[4];
        #pragma unroll
        for (int i = 0; i < 4; ++i) a[i] = *(const f32x4*)(asrc + i * 4);
        uint4 h0, h1;
        cvt16(a, h0, h1);
        *(uint4*)(A + sb0) = h0;
        *(uint4*)(A + sb1) = h1;
    }
    __syncthreads();

    for (int t = 0; t < NT; ++t) {
        const int cb = t & 1, nb = cb ^ 1;
        f32x4 a[4];
        if (t + 1 < NT) {
            const char* g = w2img + (t + 1) * 8192 + wave * 2048 + lane * 16;
            gload_lds16(g,        B + nb * 8192 + wave * 2048);
            gload_lds16(g + 1024, B + nb * 8192 + wave * 2048 + 1024);
            const float* s = asrc + (t + 1) * BK;
            #pragma unroll
            for (int i = 0; i < 4; ++i) a[i] = *(const f32x4*)(s + i * 4);
        }

        f16x8 ah0 = *(const f16x8*)(A + cb * 8192 + aoff0);
        f16x8 ah1 = *(const f16x8*)(A + cb * 8192 + aoff1);
        #pragma unroll
        for (int hj = 0; hj < 8; ++hj) {
            f16x8 bh = *(const f16x8*)(B + cb * 8192 + boff0 + hj * 1024);
            acc[0][hj] = __builtin_amdgcn_mfma_f32_16x16x32_f16(ah0, bh, acc[0][hj], 0, 0, 0);
            acc[1][hj] = __builtin_amdgcn_mfma_f32_16x16x32_f16(ah1, bh, acc[1][hj], 0, 0, 0);
        }

        if (t + 1 < NT) {
            uint4 h0, h1;
            cvt16(a, h0, h1);
            *(uint4*)(A + nb * 8192 + sb0) = h0;
            *(uint4*)(A + nb * 8192 + sb1) = h1;
        }
        __syncthreads();
    }

    // epilogue: scores.  C/D: col=l15, row=l4*4+j
    #pragma unroll
    for (int mi = 0; mi < 2; ++mi) {
        #pragma unroll
        for (int j = 0; j < 4; ++j) {
            float p = 0.f;
            #pragma unroll
            for (int hj = 0; hj < 8; ++hj) {
                float x = qv[hj] + acc[mi][hj][j];
                float e = __expf(2.f * x);
                float th = 1.f - 2.f * __builtin_amdgcn_rcpf(1.f + e);
                p += th * vv[hj];
            }
            #pragma unroll
            for (int off = 1; off < 16; off <<= 1) p += __shfl_xor(p, off);
            if (l15 == 0) {
                int r = wave * 32 + mi * 16 + l4 * 4 + j;
                score_out[m0 + r] = p;   // raw score
                sc[r] = p;
            }
        }
    }
    __syncthreads();

    // block softmax partials
    float s_val = sc[tid & 127];
    float mx = s_val;
    #pragma unroll
    for (int off = 32; off >= 1; off >>= 1) mx = fmaxf(mx, __shfl_xor(mx, off));
    if (lane == 0) red[wave] = mx;
    __syncthreads();
    float m = fmaxf(fmaxf(red[0], red[1]), fmaxf(red[2], red[3]));
    float p = __expf(s_val - m);
    if (tid < 128) pb[tid] = p;
    float ps = p;
    #pragma unroll
    for (int off = 32; off >= 1; off >>= 1) ps += __shfl_xor(ps, off);
    if (lane == 0) red[4 + wave] = ps;
    __syncthreads();
    if (tid == 0) {
        part_m[blk] = m;
        part_l[blk] = red[4] + red[5];   // waves 0,1 cover rows 0..127
    }

    // context partial GEMV: c[col] = sum_s pb[s] * keys[m0+s, col]
    int col = tid * 2;
    float c0 = 0.f, c1 = 0.f;
    const float* kb = keys + (size_t)m0 * KD + col;
    #pragma unroll 4
    for (int s = 0; s < BM; ++s) {
        float w = pb[s];
        float2 kv = *(const float2*)(kb + (size_t)s * KD);
        c0 = fmaf(w, kv.x, c0);
        c1 = fmaf(w, kv.y, c1);
    }
    *(float2*)(part_c + (size_t)blk * KD + col) = make_float2(c0, c1);
}

// ---------------------------------------------------------------- finalize
// per batch: merge 16 partials, write weights (in place over raw scores) + context
__global__ __launch_bounds__(256) void finalize_kernel(
        const float* __restrict__ part_m, const float* __restrict__ part_l,
        const float* __restrict__ part_c, float* __restrict__ ctx,
        float* __restrict__ wts) {
    int b = blockIdx.x;
    int tid = threadIdx.x;
    float M = -1e30f;
    #pragma unroll
    for (int i = 0; i < 16; ++i) M = fmaxf(M, part_m[b * 16 + i]);
    float e[16];
    float L = 0.f;
    #pragma unroll
    for (int i = 0; i < 16; ++i) {
        e[i] = __expf(part_m[b * 16 + i] - M);
        L += e[i] * part_l[b * 16 + i];
    }
    float invL = 1.f / L;
    #pragma unroll
    for (int r = 0; r < 8; ++r) {
        int s = tid + r * 256;
        float scv = wts[b * SEQ + s];
        wts[b * SEQ + s] = __expf(scv - M) * invL;
    }
    #pragma unroll
    for (int g = 0; g < 2; ++g) {
        int col = tid + g * 256;
        float acc = 0.f;
        #pragma unroll
        for (int i = 0; i < 16; ++i)
            acc += e[i] * part_c[(size_t)(b * 16 + i) * KD + col];
        ctx[b * KD + col] = acc * invL;
    }
}

// ---------------------------------------------------------------- launch
extern "C" void kernel_launch(void* const* d_in, const int* in_sizes, int n_in,
                              void* d_out, int out_size, void* d_ws, size_t ws_size,
                              hipStream_t stream) {
    const float* query = (const float*)d_in[0];
    const float* keys  = (const float*)d_in[1];
    const float* W1    = (const float*)d_in[2];
    const float* W2    = (const float*)d_in[3];
    const float* V     = (const float*)d_in[4];

    float* ctx = (float*)d_out;
    float* wts = (float*)d_out + BATCH * KD;

    char* wsb   = (char*)d_ws;
    float* qp   = (float*)wsb;                         // 16 KB
    char* w2img = wsb + 16 * 1024;                     // 128 KB
    float* part_m = (float*)(wsb + 144 * 1024);        // 2 KB
    float* part_l = (float*)(wsb + 146 * 1024);        // 2 KB
    float* part_c = (float*)(wsb + 148 * 1024);        // 1 MB

    prep_kernel<<<528, 256, 0, stream>>>(query, W1, W2, qp, w2img);
    score_ctx_kernel<<<(BATCH * SEQ) / BM, 256, 0, stream>>>(
        keys, w2img, qp, V, wts, part_m, part_l, part_c);
    finalize_kernel<<<BATCH, 256, 0, stream>>>(part_m, part_l, part_c, ctx, wts);
}